// Round 6
// baseline (148.772 us; speedup 1.0000x reference)
//
#include <hip/hip_runtime.h>

// ---------------- problem constants (fixed by setup_inputs) ----------------
constexpr int B_ = 2, N_ = 8192, M_ = 8192, Dd = 64;
constexpr int TN = 128;              // n-rows per block (4 waves, m-partitioned QK)
constexpr int TM = 64;               // ref rows per chunk
constexpr int SPLIT = 8;             // M-splits; blockIdx&7 pins split->XCD
constexpr int MCHUNK = M_ / SPLIT;   // 1024
constexpr int NCHUNKS = MCHUNK / TM; // 16
constexpr int NT = N_ / TN;          // 64
constexpr float LOG2E   = 1.4426950408889634f;
constexpr float SCALE_S = LOG2E / 64.0f;    //  dot/64    in log2 domain
constexpr float SCALE_N = -LOG2E / 128.0f;  // -|v|^2/128 in log2 domain

using s16x8 = __attribute__((ext_vector_type(8))) short;
using f32x4 = __attribute__((ext_vector_type(4))) float;
using f32x2v = __attribute__((ext_vector_type(2))) float;
using bf16x2 = __attribute__((ext_vector_type(2))) __bf16;

#if defined(__has_builtin)
#if __has_builtin(__builtin_amdgcn_exp2f)
#define EXP2(x) __builtin_amdgcn_exp2f(x)
#endif
#endif
#ifndef EXP2
#define EXP2(x) exp2f(x)
#endif

// f32 pair -> packed bf16 (RNE) via 2-wide vector fptrunc -> v_cvt_pk_bf16_f32.
__device__ __forceinline__ unsigned pk2(float lo, float hi) {
  f32x2v f;
  f[0] = lo;
  f[1] = hi;
  bf16x2 h = __builtin_convertvector(f, bf16x2);
  return __builtin_bit_cast(unsigned, h);
}
__device__ __forceinline__ f32x4 mfma16(s16x8 a, s16x8 b, f32x4 c) {
  return __builtin_amdgcn_mfma_f32_16x16x32_bf16(a, b, c, 0, 0, 0);
}
__device__ __forceinline__ float dot4(float4 f) {
  return f.x * f.x + f.y * f.y + f.z * f.z + f.w * f.w;
}

// Frag layouts (m89/m91): A/B: outer=lane&15, 8 k-contig at (lane>>4)*8.
// C/D: col = lane&15, row = (lane>>4)*4 + reg.
//
// m-partitioned QK: wave w owns S^T m-rows w*16..+15 for ALL 128 n.
//  - Y A-frags: loaded per-wave straight from global into frag layout (no ldsY).
//  - X B-frags for all 8 n-tiles register-resident (bx[8][2]).
//  - QK reads nothing cross-wave -> single barrier covers {YT,P} writes -> PV.
//
// ldsYT swizzle: element (d,m) in row d at 16B chunk F = ((m>>3) + 2*(d>>3) + (d&7)) & 7,
// offset m&7. Write side (m = w*16+l15, d = quad*8+e [+32]): combos (l15>>3, quad) map to
// 8 DISTINCT chunks (F = (w*2+(l15>>3)) + 2*quad + e) -> 2-way only (free). Read side
// (d = dt*16+l15, m-octet ks*4+quad): F = (quad + 2*(l15>>3) + (l15&7)) + 4*ks + 4*dt
// -> 2/dword (free). Round-trip verified (write F == read F).

__global__ __launch_bounds__(256, 3) void msflash_kernel(
    const float* __restrict__ pts, const float* __restrict__ ref,
    float* __restrict__ num_acc, float* __restrict__ den_acc) {
  __shared__ unsigned short ldsYT[Dd][64];    // Y chunk [d][m] swizzled (PV A)  8192 B
  __shared__ unsigned short ldsP [128][72];   // P [n][m] / X-stage / O-scratch 18432 B
  __shared__ float lds_an2[TN];               // X row norms (pre-scaled)         512 B
  __shared__ float lds_bm2[TM];               // Y row norms, wave-private slices 256 B
  // total 27,392 B

  const int tid  = threadIdx.x;
  const int w    = tid >> 6;
  const int lane = tid & 63;
  const int l15  = lane & 15, quad = lane >> 4;

  const int s  = blockIdx.x & (SPLIT - 1);
  const int r  = blockIdx.x >> 3;
  const int bb = r / NT;
  const int nt_ = r % NT;
  const int n0 = nt_ * TN;
  const int m_begin = s * MCHUNK;

  // swizzle thread-constants
  const int wbase = (w * 2 + (l15 >> 3)) + 2 * quad;      // YT write F-base (m>>3 + 2*(d>>3))
  const int mlo   = l15 & 7;                              // m&7
  const int ytr   = quad + 2 * (l15 >> 3) + (l15 & 7);    // YT read F-base

  // ---- per-wave Y loads: lane owns Y row (w*16+l15), d-slices quad*8.. (frag layout) ----
  const int myrow = w * 16 + l15;
  const float* ybase = ref + ((size_t)bb * M_ + m_begin + myrow) * Dd + quad * 8;
  float4 fv0 = ((const float4*)ybase)[0];   // d quad*8   .. +3
  float4 fv1 = ((const float4*)ybase)[1];   // d quad*8+4 .. +7
  float4 fv2 = ((const float4*)(ybase + 32))[0];  // d 32+quad*8 ..
  float4 fv3 = ((const float4*)(ybase + 32))[1];

  // ---- stage X (fp32 -> bf16) into ldsP alias + row norms ----
  unsigned short (*ldsX)[72] = (unsigned short (*)[72]) & ldsP[0][0]; // 128x72 alias
  {
    const int rowl = tid >> 1, half = tid & 1;
    const float* gp = pts + ((size_t)bb * N_ + n0 + rowl) * Dd + half * 32;
    float sq = 0.f;
    unsigned pkd[16];
#pragma unroll
    for (int i = 0; i < 8; i++) {
      float4 f = ((const float4*)gp)[i];
      sq += dot4(f);
      pkd[2 * i + 0] = pk2(f.x, f.y);
      pkd[2 * i + 1] = pk2(f.z, f.w);
    }
    sq += __shfl_xor(sq, 1);
    if (half == 0) lds_an2[rowl] = sq * SCALE_N;
    uint4* dv = (uint4*)&ldsX[rowl][half * 32];
#pragma unroll
    for (int i = 0; i < 4; i++)
      dv[i] = make_uint4(pkd[4 * i], pkd[4 * i + 1], pkd[4 * i + 2], pkd[4 * i + 3]);
  }
  __syncthreads();

  // X B-frags for ALL 8 n-tiles + per-n -|x|^2 terms (register-resident)
  s16x8 bx[8][2];
  float anr[8];
#pragma unroll
  for (int nt = 0; nt < 8; nt++) {
#pragma unroll
    for (int ks = 0; ks < 2; ks++)
      bx[nt][ks] = *(const s16x8*)&ldsX[nt * 16 + l15][ks * 32 + quad * 8];
    anr[nt] = lds_an2[nt * 16 + l15];
  }

  f32x4 o[2][4], den[2];
#pragma unroll
  for (int rt = 0; rt < 2; rt++) {
    den[rt] = f32x4{0.f, 0.f, 0.f, 0.f};
#pragma unroll
    for (int dt = 0; dt < 4; dt++) o[rt][dt] = f32x4{0.f, 0.f, 0.f, 0.f};
  }
  s16x8 ones;  // A row 0 all-ones -> D row 0 = column sums of B
#pragma unroll
  for (int j = 0; j < 8; j++) ones[j] = (l15 == 0) ? (short)0x3F80 : (short)0;

  for (int c = 0; c < NCHUNKS; c++) {
    __syncthreads();  // bar A: previous chunk's PV reads of ldsYT/ldsP done

    // ---- convert Y (regs) -> ay frags + swizzled YT writes + row norms ----
    unsigned pkA[4] = {pk2(fv0.x, fv0.y), pk2(fv0.z, fv0.w),
                       pk2(fv1.x, fv1.y), pk2(fv1.z, fv1.w)};
    unsigned pkB[4] = {pk2(fv2.x, fv2.y), pk2(fv2.z, fv2.w),
                       pk2(fv3.x, fv3.y), pk2(fv3.z, fv3.w)};
    float sq = dot4(fv0) + dot4(fv1) + dot4(fv2) + dot4(fv3);
    sq += __shfl_xor(sq, 16);
    sq += __shfl_xor(sq, 32);             // full |y_myrow|^2 in every lane
    if (quad == 0) lds_bm2[w * 16 + l15] = sq * SCALE_N;  // wave-private slice
#pragma unroll
    for (int j = 0; j < 4; j++) {
      const int d0 = quad * 8 + 2 * j;
      const int c0 = (wbase + 2 * j) & 7;
      const int c1 = (wbase + 2 * j + 1) & 7;
      ldsYT[d0     ][(c0 << 3) + mlo] = (unsigned short)pkA[j];
      ldsYT[d0 + 1 ][(c1 << 3) + mlo] = (unsigned short)(pkA[j] >> 16);
      ldsYT[d0 + 32][(c0 << 3) + mlo] = (unsigned short)pkB[j];
      ldsYT[d0 + 33][(c1 << 3) + mlo] = (unsigned short)(pkB[j] >> 16);
    }
    s16x8 ay0 = __builtin_bit_cast(s16x8, make_uint4(pkA[0], pkA[1], pkA[2], pkA[3]));
    s16x8 ay1 = __builtin_bit_cast(s16x8, make_uint4(pkB[0], pkB[1], pkB[2], pkB[3]));
    const f32x4 bmv = *(const f32x4*)&lds_bm2[w * 16 + quad * 4];  // wave-private read

    // prefetch next chunk's Y slice (hides under QK+exp+PV)
    if (c + 1 < NCHUNKS) {
      const float* yp = ybase + (size_t)(c + 1) * TM * Dd;
      fv0 = ((const float4*)yp)[0];
      fv1 = ((const float4*)yp)[1];
      fv2 = ((const float4*)(yp + 32))[0];
      fv3 = ((const float4*)(yp + 32))[1];
    }

    // ---- QK: wave-local m-slice x all n-tiles; exp2; P write [n][m] ----
#pragma unroll
    for (int nt = 0; nt < 8; nt++) {
      f32x4 acc = f32x4{0.f, 0.f, 0.f, 0.f};
      acc = mfma16(ay0, bx[nt][0], acc);
      acc = mfma16(ay1, bx[nt][1], acc);
      // acc[g] = S^T[m = w*16+quad*4+g][n = nt*16+l15]
      float e0 = EXP2(acc[0] * SCALE_S + (anr[nt] + bmv[0]));
      float e1 = EXP2(acc[1] * SCALE_S + (anr[nt] + bmv[1]));
      float e2 = EXP2(acc[2] * SCALE_S + (anr[nt] + bmv[2]));
      float e3 = EXP2(acc[3] * SCALE_S + (anr[nt] + bmv[3]));
      *(uint2*)&ldsP[nt * 16 + l15][w * 16 + quad * 4] =
          make_uint2(pk2(e0, e1), pk2(e2, e3));
    }
    __syncthreads();  // bar B: all waves' YT + P writes visible

    // ---- PV: O^T += Y^T * P^T, den += 1 * P^T ----
    s16x8 pf[2][2];
#pragma unroll
    for (int rt = 0; rt < 2; rt++)
#pragma unroll
      for (int ks = 0; ks < 2; ks++)
        pf[rt][ks] = *(const s16x8*)&ldsP[w * 32 + rt * 16 + l15][ks * 32 + quad * 8];
#pragma unroll
    for (int dt = 0; dt < 4; dt++) {
      const unsigned short* yt = &ldsYT[dt * 16 + l15][0];
      s16x8 a0 = *(const s16x8*)&yt[(((ytr + 4 * dt) & 7)) << 3];      // ks=0
      s16x8 a1 = *(const s16x8*)&yt[(((ytr + 4 + 4 * dt) & 7)) << 3];  // ks=1
#pragma unroll
      for (int rt = 0; rt < 2; rt++) {
        o[rt][dt] = mfma16(a0, pf[rt][0], o[rt][dt]);
        o[rt][dt] = mfma16(a1, pf[rt][1], o[rt][dt]);
      }
    }
#pragma unroll
    for (int rt = 0; rt < 2; rt++) {
      den[rt] = mfma16(ones, pf[rt][0], den[rt]);
      den[rt] = mfma16(ones, pf[rt][1], den[rt]);
    }
  }

  // ---- epilogue: transpose O^T through wave-private LDS scratch, coalesced atomics ----
  // o[rt][dt][g] = O[n = w*32+rt*16+l15][d = dt*16+quad*4+g]
  float* ldsO = (float*)&ldsP[w * 32][0];  // wave-private rows (only this wave reads them post-barB)
  float* nb = num_acc + ((size_t)bb * N_ + n0) * Dd;
#pragma unroll
  for (int rt = 0; rt < 2; rt++) {
#pragma unroll
    for (int dt = 0; dt < 4; dt++) {
      const int base = l15 * 66 + dt * 16 + quad * 4;
      *(float2*)&ldsO[base + 0] = make_float2(o[rt][dt][0], o[rt][dt][1]);
      *(float2*)&ldsO[base + 2] = make_float2(o[rt][dt][2], o[rt][dt][3]);
    }
    const int nrow = w * 32 + rt * 16;  // wave-private region: in-order LDS, no barrier
#pragma unroll
    for (int rr = 0; rr < 16; rr++) {
      float v = ldsO[rr * 66 + lane];
      atomicAdd(&nb[(size_t)(nrow + rr) * Dd + lane], v);  // 256B contiguous per instr
    }
    if (quad == 0)
      atomicAdd(&den_acc[(size_t)bb * N_ + n0 + nrow + l15], den[rt][0]);
  }
}

__global__ __launch_bounds__(256) void msdiv_kernel(
    const float* __restrict__ num, const float* __restrict__ den,
    float* __restrict__ out) {
  const int i = blockIdx.x * 256 + threadIdx.x;  // float4 index; grid covers exactly
  float4 v = ((const float4*)num)[i];
  const float inv = 1.0f / den[i >> 4];          // 16 float4 per 64-wide row
  ((float4*)out)[i] = make_float4(v.x * inv, v.y * inv, v.z * inv, v.w * inv);
}

extern "C" void kernel_launch(void* const* d_in, const int* in_sizes, int n_in,
                              void* d_out, int out_size, void* d_ws, size_t ws_size,
                              hipStream_t stream) {
  const float* pts = (const float*)d_in[0];
  const float* ref = (const float*)d_in[1];
  float* out = (float*)d_out;
  float* num = (float*)d_ws;                       // [B,N,64] fp32 partial numerators
  float* den = num + (size_t)B_ * N_ * Dd;         // [B,N]    fp32 partial denominators
  const size_t acc_bytes = ((size_t)B_ * N_ * Dd + (size_t)B_ * N_) * sizeof(float);

  hipMemsetAsync(d_ws, 0, acc_bytes, stream);      // ws is re-poisoned 0xAA each launch
  msflash_kernel<<<dim3(B_ * NT * SPLIT), dim3(256), 0, stream>>>(pts, ref, num, den);
  const int tot4 = B_ * N_ * Dd / 4;               // 262144
  msdiv_kernel<<<dim3(tot4 / 256), dim3(256), 0, stream>>>(num, den, out);
}

// Round 7
// 127.922 us; speedup vs baseline: 1.1630x; 1.1630x over previous
//
#include <hip/hip_runtime.h>

// ---------------- problem constants (fixed by setup_inputs) ----------------
constexpr int B_ = 2, N_ = 8192, M_ = 8192, Dd = 64;
constexpr int TN = 128;              // n-rows per block (4 waves x 32, n-partitioned)
constexpr int TM = 64;               // ref rows per chunk
constexpr int SPLIT = 8;             // M-splits; blockIdx&7 pins split->XCD
constexpr int MCHUNK = M_ / SPLIT;   // 1024
constexpr int NCHUNKS = MCHUNK / TM; // 16
constexpr int NT = N_ / TN;          // 64
constexpr float LOG2E   = 1.4426950408889634f;
constexpr float SCALE_S = LOG2E / 64.0f;    //  dot/64    in log2 domain
constexpr float SCALE_N = -LOG2E / 128.0f;  // -|v|^2/128 in log2 domain

using s16x8 = __attribute__((ext_vector_type(8))) short;
using f32x4 = __attribute__((ext_vector_type(4))) float;
using f32x2v = __attribute__((ext_vector_type(2))) float;
using bf16x2 = __attribute__((ext_vector_type(2))) __bf16;

#if defined(__has_builtin)
#if __has_builtin(__builtin_amdgcn_exp2f)
#define EXP2(x) __builtin_amdgcn_exp2f(x)
#endif
#endif
#ifndef EXP2
#define EXP2(x) exp2f(x)
#endif

// f32 pair -> packed bf16 (RNE) via 2-wide vector fptrunc -> v_cvt_pk_bf16_f32.
__device__ __forceinline__ unsigned pk2(float lo, float hi) {
  f32x2v f;
  f[0] = lo;
  f[1] = hi;
  bf16x2 h = __builtin_convertvector(f, bf16x2);
  return __builtin_bit_cast(unsigned, h);
}
__device__ __forceinline__ f32x4 mfma16(s16x8 a, s16x8 b, f32x4 c) {
  return __builtin_amdgcn_mfma_f32_16x16x32_bf16(a, b, c, 0, 0, 0);
}
__device__ __forceinline__ float dot4(float4 f) {
  return f.x * f.x + f.y * f.y + f.z * f.z + f.w * f.w;
}

// Frag layouts (m89/m91): A/B: outer=lane&15, 8 k-contig at (lane>>4)*8.
// C/D: col = lane&15, row = (lane>>4)*4 + reg.
// Structure = R4 (n-partitioned QK, 76.5us) + single-barrier double-buffer:
//   per chunk: { COMPUTE(buf p)  ||  STAGE(chunk c+1 -> buf p^1) ; barrier ; p^=1 }
// Staging VALU/LDS-writes now schedule inside the QK/exp/PV region (T3-minimum recipe)
// instead of sitting serially between two barriers (m233 2-phase stall).
//
// ldsYT swizzle (R4-proven): (d,m) at 16B chunk F=((m>>3)+2*(d>>4)+(d&7))&7, offset m&7.
// ldsPp swizzle (new): row r=rt*16+l15 (32 rows/wave), m in [0,64): octet
//   o' = ((m>>3) + (r&7)) & 7, offset m&7. Write m=ct*16+quad*4 (uint2, 8B-aligned),
//   read m=ks*32+quad*8 (b128, 16B-aligned). Same formula both sides -> round-trip exact.
// LDS: Ydbuf 18432 (also X-stage [128][72] alias + epilogue O-scratch alias)
//      + YTdbuf 16384 + P 16384 + norms 1024 = 52224 B -> 3 blocks/CU.

__global__ __launch_bounds__(256, 3) void msflash_kernel(
    const float* __restrict__ pts, const float* __restrict__ ref,
    float* __restrict__ num_acc, float* __restrict__ den_acc) {
  __shared__ unsigned short ldsY2[2][TM][72];   // Y dbuf [m][d]; X/O alias    18432 B
  __shared__ unsigned short ldsYT2[2][Dd][64];  // Y^T dbuf [d][m] swizzled    16384 B
  __shared__ unsigned short ldsPp[4][32][64];   // per-wave P [n][m] swizzled  16384 B
  __shared__ float lds_an2[TN];                 // X row norms                   512 B
  __shared__ float lds_bm2[2][TM];              // Y row norms dbuf              512 B

  const int tid  = threadIdx.x;
  const int w    = tid >> 6;
  const int lane = tid & 63;
  const int l15  = lane & 15, quad = lane >> 4;
  const int ytsw = quad + (l15 & 7);            // YT read F-base (R4)
  const int psw  = l15 & 7;                     // P swizzle r&7

  const int s  = blockIdx.x & (SPLIT - 1);
  const int r  = blockIdx.x >> 3;
  const int bb = r / NT;
  const int nt_ = r % NT;
  const int n0 = nt_ * TN;
  const int m_begin = s * MCHUNK;

  // ---- staging thread mapping (Y): 64 rows x 4 threads x 16 d each ----
  const int rowl_s = tid >> 2, q_s = tid & 3;
  const float* ybase = ref + ((size_t)bb * M_ + m_begin + rowl_s) * Dd + q_s * 16;
  float4 fv0, fv1, fv2, fv3;

  auto loadfv = [&](int cc) {
    const float* yp = ybase + (size_t)cc * TM * Dd;
    fv0 = ((const float4*)yp)[0];
    fv1 = ((const float4*)yp)[1];
    fv2 = ((const float4*)yp)[2];
    fv3 = ((const float4*)yp)[3];
  };
  auto stage = [&](int bp) {   // convert fv -> ldsY2[bp], ldsYT2[bp], lds_bm2[bp]
    unsigned pkd[8] = {pk2(fv0.x, fv0.y), pk2(fv0.z, fv0.w),
                       pk2(fv1.x, fv1.y), pk2(fv1.z, fv1.w),
                       pk2(fv2.x, fv2.y), pk2(fv2.z, fv2.w),
                       pk2(fv3.x, fv3.y), pk2(fv3.z, fv3.w)};
    float sq = dot4(fv0) + dot4(fv1) + dot4(fv2) + dot4(fv3);
    sq += __shfl_xor(sq, 1);
    sq += __shfl_xor(sq, 2);
    if (q_s == 0) lds_bm2[bp][rowl_s] = sq * SCALE_N;
    uint4* dv = (uint4*)&ldsY2[bp][rowl_s][q_s * 16];
    dv[0] = make_uint4(pkd[0], pkd[1], pkd[2], pkd[3]);
    dv[1] = make_uint4(pkd[4], pkd[5], pkd[6], pkd[7]);
    const int tsw = (rowl_s >> 3) + 2 * q_s;
    const int mlo = rowl_s & 7;
#pragma unroll
    for (int j = 0; j < 8; j++) {
      const int d0 = q_s * 16 + 2 * j;
      const int c0 = (tsw + ((2 * j) & 7)) & 7;
      const int c1 = (tsw + ((2 * j + 1) & 7)) & 7;
      ldsYT2[bp][d0][(c0 << 3) + mlo]     = (unsigned short)pkd[j];
      ldsYT2[bp][d0 + 1][(c1 << 3) + mlo] = (unsigned short)(pkd[j] >> 16);
    }
  };

  // ---- prologue: X stage into Y-dbuf alias + chunk-0 stage into buf 0 ----
  loadfv(0);
  unsigned short (*ldsX)[72] = (unsigned short (*)[72]) & ldsY2[0][0][0];  // [128][72]
  {
    const int rowl = tid >> 1, half = tid & 1;
    const float* gp = pts + ((size_t)bb * N_ + n0 + rowl) * Dd + half * 32;
    float sq = 0.f;
    unsigned pkd[16];
#pragma unroll
    for (int i = 0; i < 8; i++) {
      float4 f = ((const float4*)gp)[i];
      sq += dot4(f);
      pkd[2 * i + 0] = pk2(f.x, f.y);
      pkd[2 * i + 1] = pk2(f.z, f.w);
    }
    sq += __shfl_xor(sq, 1);
    if (half == 0) lds_an2[rowl] = sq * SCALE_N;
    uint4* dv = (uint4*)&ldsX[rowl][half * 32];
#pragma unroll
    for (int i = 0; i < 4; i++)
      dv[i] = make_uint4(pkd[4 * i], pkd[4 * i + 1], pkd[4 * i + 2], pkd[4 * i + 3]);
  }
  __syncthreads();

  // X B-frags (col = n) + per-row -|x|^2 term -> registers
  s16x8 bx[2][2];
  float anr_s[2];
#pragma unroll
  for (int rt = 0; rt < 2; rt++) {
#pragma unroll
    for (int ks = 0; ks < 2; ks++)
      bx[rt][ks] = *(const s16x8*)&ldsX[w * 32 + rt * 16 + l15][ks * 32 + quad * 8];
    anr_s[rt] = lds_an2[w * 32 + rt * 16 + l15];
  }
  __syncthreads();   // all bx reads done before chunk-0 writes overwrite the alias

  stage(0);
  loadfv(1);
  __syncthreads();   // buf 0 visible

  f32x4 o[2][4], den[2];
#pragma unroll
  for (int rt = 0; rt < 2; rt++) {
    den[rt] = f32x4{0.f, 0.f, 0.f, 0.f};
#pragma unroll
    for (int dt = 0; dt < 4; dt++) o[rt][dt] = f32x4{0.f, 0.f, 0.f, 0.f};
  }
  s16x8 ones;  // A row 0 all-ones -> D row 0 = column sums of B
#pragma unroll
  for (int j = 0; j < 8; j++) ones[j] = (l15 == 0) ? (short)0x3F80 : (short)0;

  int p = 0;
  for (int c = 0; c < NCHUNKS; ++c) {
    // ================= COMPUTE chunk c from buf p =================
    // QK: S^T tiles, A = Y[m][d] from ldsY2[p], B = bx (regs)
    f32x4 sf[2][4];
#pragma unroll
    for (int ct = 0; ct < 4; ct++) {
      s16x8 a0 = *(const s16x8*)&ldsY2[p][ct * 16 + l15][quad * 8];
      s16x8 a1 = *(const s16x8*)&ldsY2[p][ct * 16 + l15][32 + quad * 8];
#pragma unroll
      for (int rt = 0; rt < 2; rt++) {
        f32x4 acc = f32x4{0.f, 0.f, 0.f, 0.f};
        acc = mfma16(a0, bx[rt][0], acc);
        acc = mfma16(a1, bx[rt][1], acc);
        sf[rt][ct] = acc;
      }
    }
    // exp2 + swizzled P write (wave-private)
#pragma unroll
    for (int ct = 0; ct < 4; ct++) {
      f32x4 bm = *(const f32x4*)&lds_bm2[p][ct * 16 + quad * 4];
#pragma unroll
      for (int rt = 0; rt < 2; rt++) {
        float e0 = EXP2(sf[rt][ct][0] * SCALE_S + (anr_s[rt] + bm[0]));
        float e1 = EXP2(sf[rt][ct][1] * SCALE_S + (anr_s[rt] + bm[1]));
        float e2 = EXP2(sf[rt][ct][2] * SCALE_S + (anr_s[rt] + bm[2]));
        float e3 = EXP2(sf[rt][ct][3] * SCALE_S + (anr_s[rt] + bm[3]));
        const int oW = (2 * ct + (quad >> 1) + psw) & 7;   // m = ct*16+quad*4
        *(uint2*)&ldsPp[w][rt * 16 + l15][(oW << 3) + (quad & 1) * 4] =
            make_uint2(pk2(e0, e1), pk2(e2, e3));
      }
    }
    // P read (swizzled b128) + PV + den
    s16x8 pf[2][2];
#pragma unroll
    for (int rt = 0; rt < 2; rt++)
#pragma unroll
      for (int ks = 0; ks < 2; ks++) {
        const int oR = (4 * ks + quad + psw) & 7;          // m = ks*32+quad*8
        pf[rt][ks] = *(const s16x8*)&ldsPp[w][rt * 16 + l15][oR << 3];
      }
#pragma unroll
    for (int dt = 0; dt < 4; dt++) {
      const unsigned short* yt = &ldsYT2[p][dt * 16 + l15][0];
      s16x8 a0 = *(const s16x8*)&yt[((ytsw + 2 * dt) & 7) << 3];       // ks=0
      s16x8 a1 = *(const s16x8*)&yt[((ytsw + 4 + 2 * dt) & 7) << 3];   // ks=1
#pragma unroll
      for (int rt = 0; rt < 2; rt++) {
        o[rt][dt] = mfma16(a0, pf[rt][0], o[rt][dt]);
        o[rt][dt] = mfma16(a1, pf[rt][1], o[rt][dt]);
      }
    }
#pragma unroll
    for (int rt = 0; rt < 2; rt++) {
      den[rt] = mfma16(ones, pf[rt][0], den[rt]);
      den[rt] = mfma16(ones, pf[rt][1], den[rt]);
    }
    // ================= STAGE chunk c+1 into buf p^1 (overlapped) =================
    // Branchless: at c = NCHUNKS-1 this restages chunk 15 into the dead buffer
    // (never read) and reloads it - trades ~16KB L2 reads for a single-BB body.
    stage(p ^ 1);
    loadfv(c + 2 < NCHUNKS ? c + 2 : NCHUNKS - 1);
    __syncthreads();
    p ^= 1;
  }

  // ---- epilogue: transpose O^T via wave-private scratch over the Y-dbuf alias ----
  // o[rt][dt][g] = O[n = w*32+rt*16+l15][d = dt*16+quad*4+g]
  float* ldsO = (float*)&ldsY2[0][0][0] + (size_t)w * 1152;  // 32 rows * 36 floats/wave
  float* nb = num_acc + ((size_t)bb * N_ + n0) * Dd;
#pragma unroll
  for (int rt = 0; rt < 2; rt++) {
#pragma unroll
    for (int dt = 0; dt < 4; dt++) {
      const int base = l15 * 66 + dt * 16 + quad * 4;
      *(float2*)&ldsO[base + 0] = make_float2(o[rt][dt][0], o[rt][dt][1]);
      *(float2*)&ldsO[base + 2] = make_float2(o[rt][dt][2], o[rt][dt][3]);
    }
    const int nrow = w * 32 + rt * 16;  // wave-private region: in-order LDS, no barrier
#pragma unroll
    for (int rr = 0; rr < 16; rr++) {
      float v = ldsO[rr * 66 + lane];
      atomicAdd(&nb[(size_t)(nrow + rr) * Dd + lane], v);  // 256B contiguous per instr
    }
    if (quad == 0)
      atomicAdd(&den_acc[(size_t)bb * N_ + n0 + nrow + l15], den[rt][0]);
  }
}

__global__ __launch_bounds__(256) void msdiv_kernel(
    const float* __restrict__ num, const float* __restrict__ den,
    float* __restrict__ out) {
  const int i = blockIdx.x * 256 + threadIdx.x;  // float4 index; grid covers exactly
  float4 v = ((const float4*)num)[i];
  const float inv = 1.0f / den[i >> 4];          // 16 float4 per 64-wide row
  ((float4*)out)[i] = make_float4(v.x * inv, v.y * inv, v.z * inv, v.w * inv);
}

extern "C" void kernel_launch(void* const* d_in, const int* in_sizes, int n_in,
                              void* d_out, int out_size, void* d_ws, size_t ws_size,
                              hipStream_t stream) {
  const float* pts = (const float*)d_in[0];
  const float* ref = (const float*)d_in[1];
  float* out = (float*)d_out;
  float* num = (float*)d_ws;                       // [B,N,64] fp32 partial numerators
  float* den = num + (size_t)B_ * N_ * Dd;         // [B,N]    fp32 partial denominators
  const size_t acc_bytes = ((size_t)B_ * N_ * Dd + (size_t)B_ * N_) * sizeof(float);

  hipMemsetAsync(d_ws, 0, acc_bytes, stream);      // ws is re-poisoned 0xAA each launch
  msflash_kernel<<<dim3(B_ * NT * SPLIT), dim3(256), 0, stream>>>(pts, ref, num, den);
  const int tot4 = B_ * N_ * Dd / 4;               // 262144
  msdiv_kernel<<<dim3(tot4 / 256), dim3(256), 0, stream>>>(num, den, out);
}